// Round 17
// baseline (117.663 us; speedup 1.0000x reference)
//
#include <hip/hip_runtime.h>

// Problem constants
#define S_LEN   1024
#define NH      16
#define HD      64
#define BATCHN  8
#define DMODEL  1024
#define HALF_W  16          // window//2

typedef __attribute__((ext_vector_type(8))) short bf16x8;   // 8 bf16 = 4 VGPRs
typedef __attribute__((ext_vector_type(4))) float f32x4;

__device__ __forceinline__ unsigned short f2bf(float f) {
  unsigned u = __builtin_bit_cast(unsigned, f);
  u += 0x7fffu + ((u >> 16) & 1u);          // round-to-nearest-even
  return (unsigned short)(u >> 16);
}
__device__ __forceinline__ float bf2f(unsigned short h) {
  return __builtin_bit_cast(float, ((unsigned)h) << 16);
}

__device__ __forceinline__ void gload_lds16(const void* g, void* l) {
  __builtin_amdgcn_global_load_lds(
      (const __attribute__((address_space(1))) void*)g,
      (__attribute__((address_space(3))) void*)l, 16, 0, 0);
}

// ---------------------------------------------------------------------------
// Fused f32 -> bf16 conversion for x, w_in, w_out (one launch, grid-stride)
// ---------------------------------------------------------------------------
#define XT  2097152                  // 8192*1024/4
#define WIT  786432                  // 3072*1024/4
#define WOT  262144                  // 1024*1024/4
__global__ __launch_bounds__(256) void cvt_all_kernel(
    const float* __restrict__ x, const float* __restrict__ wi,
    const float* __restrict__ wo,
    unsigned short* __restrict__ xb, unsigned short* __restrict__ wib,
    unsigned short* __restrict__ wob) {
  const int total = XT + WIT + WOT;
  for (int t = blockIdx.x * 256 + threadIdx.x; t < total; t += 2048 * 256) {
    const float* in; unsigned short* out; int i;
    if (t < XT)            { in = x;  out = xb;  i = t; }
    else if (t < XT + WIT) { in = wi; out = wib; i = t - XT; }
    else                   { in = wo; out = wob; i = t - XT - WIT; }
    float4 v = reinterpret_cast<const float4*>(in)[i];
    ushort4 o = make_ushort4(f2bf(v.x), f2bf(v.y), f2bf(v.z), f2bf(v.w));
    reinterpret_cast<ushort4*>(out)[i] = o;
  }
}

#define MFMA_BF16 __builtin_amdgcn_mfma_f32_16x16x32_bf16

// ---------------------------------------------------------------------------
// In-proj GEMM (R17, 2-deep occupancy): C[8192,3072]bf16 = A*B^T + bias.
// Tile 128x256, grid 64x12 = 768, 4 waves (256 thr), per-wave 128x64
// (32 MFMA/gate, two 16-clusters). K in 32-col slabs; THREE 24KB slots =
// 72KB LDS -> 2 blocks/CU resident: one block's gate drain hides under the
// co-resident block's MFMA (m114 overlap — R10's 160KB forced 1-deep).
// 6 gloads/thread/slab; prologue 2 slabs; gate vmcnt(6) (p<31), vmcnt(0)
// tail; STG(p+2) distance-2 (slot race-free mod 3). R8 swizzle unchanged.
// ---------------------------------------------------------------------------
__global__ __launch_bounds__(256, 2) void gemm_inproj_kernel(
    const unsigned short* __restrict__ A,
    const unsigned short* __restrict__ B,
    const float* __restrict__ bias,
    unsigned short* __restrict__ C) {
  __shared__ __align__(16) unsigned short lds[36864];   // 72 KiB = 3 x 24KB

  const int tid  = threadIdx.x;
  const int lane = tid & 63;
  const int wv   = tid >> 6;       // 0..3  (N: 4 x 64)
  const int lgrp = lane >> 4;      // 0..3
  const int l15  = lane & 15;

  // T1: bijective XCD swizzle (nwg = 768, 768 % 8 == 0, cpx = 96)
  const int sid = (blockIdx.x & 7) * 96 + (blockIdx.x >> 3);
  const int tileM = (sid / 12) * 128;    // 64 M-tiles
  const int tileN = (sid % 12) * 256;    // 12 N-tiles

  // staging: thread t -> slab row t>>2 (0..63), chunk t&3; source col
  // pre-swizzled by f(row) = (row>>1)&3 = (t>>3)&3 (invariant under +64 rows)
  const int srow = tid >> 2;
  const int scol = ((tid & 3) ^ ((tid >> 3) & 3)) * 8;
  const unsigned short* gA_s = A + (size_t)(tileM + srow) * 1024 + scol;
  const unsigned short* gB_s = B + (size_t)(tileN + srow) * 1024 + scol;

  // fragment read bases: chunk = lgrp ^ ((l15>>1)&3)  (conflict-free 2-way)
  const int fch  = (lgrp ^ ((l15 >> 1) & 3)) * 8;
  const int arow = l15 * 32 + fch;                   // A slab (+mt*512)
  const int brow = 4096 + (wv * 64 + l15) * 32 + fch; // B slab (+nt*512)

  f32x4 acc[32] = {};   // [mt 0..7][nt 0..3] -> acc[mt*4+nt]

  // slab S -> slot S%3 @ (S%3)*12288: A 128x32 @0 (4096 ush), B 256x32 @4096
#define STG(S) do { const int _q = (S) % 3;                                \
    const unsigned short* _ga = gA_s + (S) * 32;                           \
    const unsigned short* _gb = gB_s + (S) * 32;                           \
    gload_lds16(_ga,          &lds[_q * 12288 + tid * 8]);                 \
    gload_lds16(_ga + 65536,  &lds[_q * 12288 + 2048 + tid * 8]);          \
    gload_lds16(_gb,          &lds[_q * 12288 + 4096 + tid * 8]);          \
    gload_lds16(_gb + 65536,  &lds[_q * 12288 + 6144 + tid * 8]);          \
    gload_lds16(_gb + 131072, &lds[_q * 12288 + 8192 + tid * 8]);          \
    gload_lds16(_gb + 196608, &lds[_q * 12288 + 10240 + tid * 8]);         \
  } while (0)

#define M16(MB)                                                            \
    acc[(MB+0)*4+0] = MFMA_BF16(a0_, b0_, acc[(MB+0)*4+0], 0, 0, 0);       \
    acc[(MB+0)*4+1] = MFMA_BF16(a0_, b1_, acc[(MB+0)*4+1], 0, 0, 0);       \
    acc[(MB+0)*4+2] = MFMA_BF16(a0_, b2_, acc[(MB+0)*4+2], 0, 0, 0);       \
    acc[(MB+0)*4+3] = MFMA_BF16(a0_, b3_, acc[(MB+0)*4+3], 0, 0, 0);       \
    acc[(MB+1)*4+0] = MFMA_BF16(a1_, b0_, acc[(MB+1)*4+0], 0, 0, 0);       \
    acc[(MB+1)*4+1] = MFMA_BF16(a1_, b1_, acc[(MB+1)*4+1], 0, 0, 0);       \
    acc[(MB+1)*4+2] = MFMA_BF16(a1_, b2_, acc[(MB+1)*4+2], 0, 0, 0);       \
    acc[(MB+1)*4+3] = MFMA_BF16(a1_, b3_, acc[(MB+1)*4+3], 0, 0, 0);       \
    acc[(MB+2)*4+0] = MFMA_BF16(a2_, b0_, acc[(MB+2)*4+0], 0, 0, 0);       \
    acc[(MB+2)*4+1] = MFMA_BF16(a2_, b1_, acc[(MB+2)*4+1], 0, 0, 0);       \
    acc[(MB+2)*4+2] = MFMA_BF16(a2_, b2_, acc[(MB+2)*4+2], 0, 0, 0);       \
    acc[(MB+2)*4+3] = MFMA_BF16(a2_, b3_, acc[(MB+2)*4+3], 0, 0, 0);       \
    acc[(MB+3)*4+0] = MFMA_BF16(a3_, b0_, acc[(MB+3)*4+0], 0, 0, 0);       \
    acc[(MB+3)*4+1] = MFMA_BF16(a3_, b1_, acc[(MB+3)*4+1], 0, 0, 0);       \
    acc[(MB+3)*4+2] = MFMA_BF16(a3_, b2_, acc[(MB+3)*4+2], 0, 0, 0);       \
    acc[(MB+3)*4+3] = MFMA_BF16(a3_, b3_, acc[(MB+3)*4+3], 0, 0, 0);

  // prologue: slabs 0,1 -> 12 outstanding
  STG(0); STG(1);

#pragma unroll 1
  for (int p = 0; p < 32; ++p) {
    if (p < 31) { asm volatile("s_waitcnt vmcnt(6)" ::: "memory"); }
    else        { asm volatile("s_waitcnt vmcnt(0)" ::: "memory"); }
    __builtin_amdgcn_sched_barrier(0);
    __builtin_amdgcn_s_barrier();

    if (p <= 29) STG(p + 2);

    const int slotb = (p % 3) * 12288;
    const unsigned short* pa = &lds[slotb + arow];
    const unsigned short* pb = &lds[slotb + brow];

    bf16x8 b0_ = *(const bf16x8*)(pb);
    bf16x8 b1_ = *(const bf16x8*)(pb + 512);
    bf16x8 b2_ = *(const bf16x8*)(pb + 1024);
    bf16x8 b3_ = *(const bf16x8*)(pb + 1536);
    bf16x8 a0_ = *(const bf16x8*)(pa);
    bf16x8 a1_ = *(const bf16x8*)(pa + 512);
    bf16x8 a2_ = *(const bf16x8*)(pa + 1024);
    bf16x8 a3_ = *(const bf16x8*)(pa + 1536);
    asm volatile("s_waitcnt lgkmcnt(0)" ::: "memory");
    __builtin_amdgcn_sched_barrier(0);
    __builtin_amdgcn_s_setprio(1);
    M16(0)
    __builtin_amdgcn_s_setprio(0);

    a0_ = *(const bf16x8*)(pa + 2048);
    a1_ = *(const bf16x8*)(pa + 2560);
    a2_ = *(const bf16x8*)(pa + 3072);
    a3_ = *(const bf16x8*)(pa + 3584);
    asm volatile("s_waitcnt lgkmcnt(0)" ::: "memory");
    __builtin_amdgcn_sched_barrier(0);
    __builtin_amdgcn_s_setprio(1);
    M16(4)
    __builtin_amdgcn_s_setprio(0);
  }
#undef STG
#undef M16

  // epilogue: C/D layout col = lane&15 (B-row), row = lgrp*4 + rr (A-row)
#pragma unroll
  for (int nt = 0; nt < 4; ++nt) {
    const int col = tileN + wv * 64 + nt * 16 + l15;
    const float bs = bias[col];
#pragma unroll
    for (int mt = 0; mt < 8; ++mt) {
      const int row0 = tileM + mt * 16 + lgrp * 4;
#pragma unroll
      for (int rr = 0; rr < 4; ++rr)
        C[(size_t)(row0 + rr) * 3072 + col] = f2bf(acc[mt * 4 + nt][rr] + bs);
    }
  }
}

// ---------------------------------------------------------------------------
// Out-proj GEMM (R13/R16-verified, frozen): C[8192,1024]f32 = A*B^T + bias.
// Tile 128x256, grid 256, 8 waves, 3 full-K-tile slots (144KB), vmcnt(6).
// ---------------------------------------------------------------------------
__global__ __launch_bounds__(512, 2) void gemm_outproj_kernel(
    const unsigned short* __restrict__ A,
    const unsigned short* __restrict__ B,
    const float* __restrict__ bias,
    float* __restrict__ Cv) {
  __shared__ __align__(16) unsigned short lds[73728];   // 144 KiB

  const int tid  = threadIdx.x;
  const int lane = tid & 63;
  const int wid  = tid >> 6;
  const int wm   = wid >> 2;       // 0..1  (M: 2 x 64)
  const int wn   = wid & 3;        // 0..3  (N: 4 x 64)
  const int lgrp = lane >> 4;
  const int l15  = lane & 15;

  const int sid = (blockIdx.x & 7) * 32 + (blockIdx.x >> 3);   // nwg = 256
  const int tileM = (sid >> 2) * 128;   // 64 M-tiles
  const int tileN = (sid & 3) * 256;    // 4 N-tiles

  const int srow = tid >> 2;
  const int scol = ((tid & 3) ^ ((tid >> 3) & 3)) * 8;
  const unsigned short* gA_s = A + (size_t)(tileM + srow) * 1024 + scol;
  const unsigned short* gB_s = B + (size_t)(tileN + srow) * 1024 + scol;

  const int fch  = (lgrp ^ ((l15 >> 1) & 3)) * 8;
  const int arow = (wm * 64 + l15) * 32 + fch;   // within 128x32 A slab
  const int brow = (wn * 64 + l15) * 32 + fch;   // within 256x32 B slab

  f32x4 acc[4][4] = {};

#define STG(T) do { const int _q = (T) % 3;                                \
    const unsigned short* _ga = gA_s + (T) * 64;                           \
    const unsigned short* _gb = gB_s + (T) * 64;                           \
    gload_lds16(_ga,               &lds[_q * 24576 + tid * 8]);            \
    gload_lds16(_ga + 32,          &lds[_q * 24576 + 4096 + tid * 8]);     \
    gload_lds16(_gb,               &lds[_q * 24576 + 8192 + tid * 8]);     \
    gload_lds16(_gb + 131072,      &lds[_q * 24576 + 12288 + tid * 8]);    \
    gload_lds16(_gb + 32,          &lds[_q * 24576 + 16384 + tid * 8]);    \
    gload_lds16(_gb + 131072 + 32, &lds[_q * 24576 + 20480 + tid * 8]);    \
  } while (0)

#define SUB16(KH) do {                                                     \
    const unsigned short* _pa = &lds[slotb + (KH) * 4096 + arow];          \
    const unsigned short* _pb = &lds[slotb + 8192 + (KH) * 8192 + brow];   \
    bf16x8 a0_ = *(const bf16x8*)(_pa);                                    \
    bf16x8 a1_ = *(const bf16x8*)(_pa + 512);                              \
    bf16x8 a2_ = *(const bf16x8*)(_pa + 1024);                             \
    bf16x8 a3_ = *(const bf16x8*)(_pa + 1536);                             \
    bf16x8 nb0 = *(const bf16x8*)(_pb);                                    \
    bf16x8 nb1 = *(const bf16x8*)(_pb + 512);                              \
    bf16x8 nb2 = *(const bf16x8*)(_pb + 1024);                             \
    bf16x8 nb3 = *(const bf16x8*)(_pb + 1536);                             \
    asm volatile("s_waitcnt lgkmcnt(0)" ::: "memory");                     \
    __builtin_amdgcn_sched_barrier(0);                                     \
    __builtin_amdgcn_s_setprio(1);                                         \
    acc[0][0] = MFMA_BF16(a0_, nb0, acc[0][0], 0, 0, 0);                   \
    acc[0][1] = MFMA_BF16(a0_, nb1, acc[0][1], 0, 0, 0);                   \
    acc[0][2] = MFMA_BF16(a0_, nb2, acc[0][2], 0, 0, 0);                   \
    acc[0][3] = MFMA_BF16(a0_, nb3, acc[0][3], 0, 0, 0);                   \
    acc[1][0] = MFMA_BF16(a1_, nb0, acc[1][0], 0, 0, 0);                   \
    acc[1][1] = MFMA_BF16(a1_, nb1, acc[1][1], 0, 0, 0);                   \
    acc[1][2] = MFMA_BF16(a1_, nb2, acc[1][2], 0, 0, 0);                   \
    acc[1][3] = MFMA_BF16(a1_, nb3, acc[1][3], 0, 0, 0);                   \
    acc[2][0] = MFMA_BF16(a2_, nb0, acc[2][0], 0, 0, 0);                   \
    acc[2][1] = MFMA_BF16(a2_, nb1, acc[2][1], 0, 0, 0);                   \
    acc[2][2] = MFMA_BF16(a2_, nb2, acc[2][2], 0, 0, 0);                   \
    acc[2][3] = MFMA_BF16(a2_, nb3, acc[2][3], 0, 0, 0);                   \
    acc[3][0] = MFMA_BF16(a3_, nb0, acc[3][0], 0, 0, 0);                   \
    acc[3][1] = MFMA_BF16(a3_, nb1, acc[3][1], 0, 0, 0);                   \
    acc[3][2] = MFMA_BF16(a3_, nb2, acc[3][2], 0, 0, 0);                   \
    acc[3][3] = MFMA_BF16(a3_, nb3, acc[3][3], 0, 0, 0);                   \
    __builtin_amdgcn_s_setprio(0);                                         \
  } while (0)

  // prologue: K-tiles 0,1 -> 12 outstanding
  STG(0); STG(1);

#pragma unroll 1
  for (int p = 0; p < 16; ++p) {
    if (p < 15) { asm volatile("s_waitcnt vmcnt(6)" ::: "memory"); }
    else        { asm volatile("s_waitcnt vmcnt(0)" ::: "memory"); }
    __builtin_amdgcn_sched_barrier(0);
    __builtin_amdgcn_s_barrier();

    if (p <= 13) STG(p + 2);

    const int slotb = (p % 3) * 24576;
    SUB16(0);
    SUB16(1);
  }
#undef STG
#undef SUB16

#pragma unroll
  for (int nt = 0; nt < 4; ++nt) {
    const int col = tileN + wn * 64 + nt * 16 + l15;
    const float bs = bias[col];
#pragma unroll
    for (int mt = 0; mt < 4; ++mt) {
      const int row0 = tileM + wm * 64 + mt * 16 + lgrp * 4;
#pragma unroll
      for (int rr = 0; rr < 4; ++rr)
        Cv[(size_t)(row0 + rr) * 1024 + col] = acc[mt][nt][rr] + bs;
    }
  }
}

// ---------------------------------------------------------------------------
// Windowed attention v3 (MFMA). Block = (b, h, 64-query tile), 4 waves.
// ---------------------------------------------------------------------------
#define KST 72    // sK/sQ stride (bf16): 144B rows -> 2-way bank alias (free)
#define PST 104   // sVT/sP stride (bf16): 208B rows -> uniform 2-way

__global__ __launch_bounds__(256) void attn_local_kernel(
    const unsigned short* __restrict__ qkv, unsigned short* __restrict__ ctx) {
  __shared__ __align__(16) unsigned short sKP[96 * KST];   // K, later P
  __shared__ __align__(16) unsigned short sQ[64 * KST];
  __shared__ __align__(16) unsigned short sVT[64 * PST];

  const int tid  = threadIdx.x;
  const int lane = tid & 63;
  const int wid  = tid >> 6;
  const int qc   = lane & 15;        // query col within wave's 16
  const int lgrp = lane >> 4;        // 0..3

  const int qb = blockIdx.x & 15;    // S/64 = 16
  const int h  = (blockIdx.x >> 4) & 15;
  const int b  = blockIdx.x >> 8;
  const int i0 = qb * 64;

  const unsigned short* hb = qkv + (size_t)b * S_LEN * 3072 + (size_t)h * HD;

  // ---- stage K [96][KST] and V^T [64][PST] ----
#pragma unroll
  for (int it = 0; it < 3; ++it) {
    int c  = it * 256 + tid;         // 0..767
    int r  = c >> 3;                 // key row 0..95
    int d0 = (c & 7) * 8;            // dim chunk
    int j  = i0 - 16 + r;
    bf16x8 kv = {}, vv = {};
    if (0 <= j && j < S_LEN) {
      const unsigned short* rp = hb + (size_t)j * 3072;
      kv = *reinterpret_cast<const bf16x8*>(rp + DMODEL + d0);
      vv = *reinterpret_cast<const bf16x8*>(rp + 2 * DMODEL + d0);
    }
    *reinterpret_cast<bf16x8*>(&sKP[r * KST + d0]) = kv;
#pragma unroll
    for (int jj = 0; jj < 8; ++jj) {
      int dd = (jj + c) & 7;
      sVT[(d0 + dd) * PST + r] = (unsigned short)vv[dd];
    }
  }
  // ---- stage Q [64][KST] ----
#pragma unroll
  for (int it = 0; it < 2; ++it) {
    int c  = it * 256 + tid;         // 0..511
    int r  = c >> 3;                 // query row 0..63
    int d0 = (c & 7) * 8;
    bf16x8 qv = *reinterpret_cast<const bf16x8*>(hb + (size_t)(i0 + r) * 3072 + d0);
    *reinterpret_cast<bf16x8*>(&sQ[r * KST + d0]) = qv;
  }
  __syncthreads();

  const int q0 = wid * 16;

  // ---- phase 1: S^T = K @ Q^T  (12 MFMA) ----
  bf16x8 bq[2];
#pragma unroll
  for (int ks = 0; ks < 2; ++ks)
    bq[ks] = *reinterpret_cast<const bf16x8*>(
        &sQ[(q0 + qc) * KST + ks * 32 + lgrp * 8]);

  f32x4 st[6] = {};
#pragma unroll
  for (int kt = 0; kt < 6; ++kt) {
#pragma unroll
    for (int ks = 0; ks < 2; ++ks) {
      bf16x8 fa = *reinterpret_cast<const bf16x8*>(
          &sKP[(kt * 16 + qc) * KST + ks * 32 + lgrp * 8]);
      st[kt] = __builtin_amdgcn_mfma_f32_16x16x32_bf16(fa, bq[ks], st[kt], 0, 0, 0);
    }
  }
  __syncthreads();   // all waves done reading sKP before P overlays it

  // ---- mask + softmax ----
  const int q = q0 + qc;
  float pv[6][4];
  float mx = -3.0e38f;
#pragma unroll
  for (int kt = 0; kt < 6; ++kt)
#pragma unroll
    for (int rr = 0; rr < 4; ++rr) {
      int kk = kt * 16 + lgrp * 4 + rr;     // local key 0..95
      int j  = i0 - 16 + kk;
      bool ok = (j >= 0) && (j < S_LEN) && (kk >= q) && (kk <= q + 32);
      float s = ok ? st[kt][rr] * 0.125f : -3.0e38f;
      pv[kt][rr] = s;
      mx = fmaxf(mx, s);
    }
  mx = fmaxf(mx, __shfl_xor(mx, 16, 64));
  mx = fmaxf(mx, __shfl_xor(mx, 32, 64));

  float rsum = 0.f;
#pragma unroll
  for (int kt = 0; kt < 6; ++kt)
#pragma unroll
    for (int rr = 0; rr < 4; ++rr) {
      float p = __expf(pv[kt][rr] - mx);
      pv[kt][rr] = p;
      rsum += p;
    }
  rsum += __shfl_xor(rsum, 16, 64);
  rsum += __shfl_xor(rsum, 32, 64);
  const float inv = 1.0f / rsum;

  // ---- write unnormalized P bf16 into sP = sKP, layout [q][k] stride PST ----
  unsigned short* sP = sKP;
#pragma unroll
  for (int kt = 0; kt < 6; ++kt) {
    ushort4 w = make_ushort4(f2bf(pv[kt][0]), f2bf(pv[kt][1]),
                             f2bf(pv[kt][2]), f2bf(pv[kt][3]));
    *reinterpret_cast<ushort4*>(&sP[(q0 + qc) * PST + kt * 16 + lgrp * 4]) = w;
  }

  // ---- phase 2: ctx^T = V^T @ P^T  (12 MFMA) ----
  bf16x8 pb[3];
#pragma unroll
  for (int ks = 0; ks < 3; ++ks)
    pb[ks] = *reinterpret_cast<const bf16x8*>(
        &sP[(q0 + qc) * PST + ks * 32 + lgrp * 8]);

  f32x4 ct[4] = {};
#pragma unroll
  for (int dt = 0; dt < 4; ++dt)
#pragma unroll
    for (int ks = 0; ks < 3; ++ks) {
      bf16x8 fa = *reinterpret_cast<const bf16x8*>(
          &sVT[(dt * 16 + qc) * PST + ks * 32 + lgrp * 8]);
      ct[dt] = __builtin_amdgcn_mfma_f32_16x16x32_bf16(fa, pb[ks], ct[dt], 0, 0, 0);
    }

  // ---- epilogue ----
  unsigned short* op =
      ctx + ((size_t)b * S_LEN + i0 + q0 + qc) * DMODEL + h * HD;
#pragma unroll
  for (int dt = 0; dt < 4; ++dt) {
    ushort4 w = make_ushort4(
        f2bf(ct[dt][0] * inv), f2bf(ct[dt][1] * inv),
        f2bf(ct[dt][2] * inv), f2bf(ct[dt][3] * inv));
    *reinterpret_cast<ushort4*>(op + dt * 16 + lgrp * 4) = w;
  }
}

// ---------------------------------------------------------------------------
extern "C" void kernel_launch(void* const* d_in, const int* in_sizes, int n_in,
                              void* d_out, int out_size, void* d_ws, size_t ws_size,
                              hipStream_t stream) {
  const float* x     = (const float*)d_in[0];
  const float* w_in  = (const float*)d_in[1];
  const float* b_in  = (const float*)d_in[2];
  const float* w_out = (const float*)d_in[3];
  const float* b_out = (const float*)d_in[4];
  float* out = (float*)d_out;

  // workspace layout (bf16 = ushort), total ~92 MB
  unsigned short* xb   = (unsigned short*)d_ws;
  unsigned short* wib  = xb  + (size_t)8192 * 1024;
  unsigned short* wob  = wib + (size_t)3072 * 1024;
  unsigned short* qkv  = wob + (size_t)1024 * 1024;
  unsigned short* ctxb = qkv + (size_t)8192 * 3072;

  // fused f32->bf16 conversion (one launch)
  cvt_all_kernel<<<2048, 256, 0, stream>>>(x, w_in, w_out, xb, wib, wob);

  // QKV = x @ w_in^T + b_in -> [8192, 3072] bf16; tile 128x256, grid 768 (2-deep)
  gemm_inproj_kernel<<<768, 256, 0, stream>>>(xb, wib, b_in, qkv);

  // windowed attention -> ctx [8192, 1024] bf16
  attn_local_kernel<<<BATCHN * NH * (S_LEN / 64), 256, 0, stream>>>(qkv, ctxb);

  // out = ctx @ w_out^T + b_out -> [8192, 1024] f32; tile 128x256, grid 256
  gemm_outproj_kernel<<<256, 512, 0, stream>>>(ctxb, wob, b_out, out);
}

// Round 18
// 112.870 us; speedup vs baseline: 1.0425x; 1.0425x over previous
//
#include <hip/hip_runtime.h>

// Problem constants
#define S_LEN   1024
#define NH      16
#define HD      64
#define BATCHN  8
#define DMODEL  1024
#define HALF_W  16          // window//2

typedef __attribute__((ext_vector_type(8))) short bf16x8;   // 8 bf16 = 4 VGPRs
typedef __attribute__((ext_vector_type(4))) float f32x4;

__device__ __forceinline__ unsigned short f2bf(float f) {
  unsigned u = __builtin_bit_cast(unsigned, f);
  u += 0x7fffu + ((u >> 16) & 1u);          // round-to-nearest-even
  return (unsigned short)(u >> 16);
}
__device__ __forceinline__ float bf2f(unsigned short h) {
  return __builtin_bit_cast(float, ((unsigned)h) << 16);
}

__device__ __forceinline__ void gload_lds16(const void* g, void* l) {
  __builtin_amdgcn_global_load_lds(
      (const __attribute__((address_space(1))) void*)g,
      (__attribute__((address_space(3))) void*)l, 16, 0, 0);
}

// ---------------------------------------------------------------------------
// Fused f32 -> bf16 conversion for x, w_in, w_out (one launch, grid-stride)
// ---------------------------------------------------------------------------
#define XT  2097152                  // 8192*1024/4
#define WIT  786432                  // 3072*1024/4
#define WOT  262144                  // 1024*1024/4
__global__ __launch_bounds__(256) void cvt_all_kernel(
    const float* __restrict__ x, const float* __restrict__ wi,
    const float* __restrict__ wo,
    unsigned short* __restrict__ xb, unsigned short* __restrict__ wib,
    unsigned short* __restrict__ wob) {
  const int total = XT + WIT + WOT;
  for (int t = blockIdx.x * 256 + threadIdx.x; t < total; t += 2048 * 256) {
    const float* in; unsigned short* out; int i;
    if (t < XT)            { in = x;  out = xb;  i = t; }
    else if (t < XT + WIT) { in = wi; out = wib; i = t - XT; }
    else                   { in = wo; out = wob; i = t - XT - WIT; }
    float4 v = reinterpret_cast<const float4*>(in)[i];
    ushort4 o = make_ushort4(f2bf(v.x), f2bf(v.y), f2bf(v.z), f2bf(v.w));
    reinterpret_cast<ushort4*>(out)[i] = o;
  }
}

#define MFMA_BF16 __builtin_amdgcn_mfma_f32_16x16x32_bf16

// ---------------------------------------------------------------------------
// In-proj GEMM (exact R10/R16, verified 61us steady / 845 TF): tile 256x384,
// grid 256 (1 CU round), 8 waves 2Mx4N, per-wave 128x96 (48 MFMA/gate),
// K in 32-col slabs, 4 LDS slots (160KB), R8 swizzle (0 conflicts),
// distance-3 prefetch, gate vmcnt(10).
// Lever inventory (all tested, all worse): read-batching (R12 +15%),
// cross-phase reg prefetch (R11 spill), 2-deep occupancy w/ smaller tile
// (R17: FETCH +78%, reuse loss dominates). This config is the optimum.
// ---------------------------------------------------------------------------
__global__ __launch_bounds__(512, 2) void gemm_inproj_kernel(
    const unsigned short* __restrict__ A,
    const unsigned short* __restrict__ B,
    const float* __restrict__ bias,
    unsigned short* __restrict__ C) {
  __shared__ __align__(16) unsigned short lds[81920];   // 160 KiB

  const int tid  = threadIdx.x;
  const int lane = tid & 63;
  const int wid  = tid >> 6;       // 0..7
  const int wm   = wid >> 2;       // 0..1  (M: 2 x 128)
  const int wn   = wid & 3;        // 0..3  (N: 4 x 96)
  const int lgrp = lane >> 4;      // 0..3
  const int l15  = lane & 15;

  // T1: bijective XCD swizzle (nwg = 256)
  const int sid = (blockIdx.x & 7) * 32 + (blockIdx.x >> 3);
  const int tileM = (sid >> 3) * 256;    // 32 M-tiles
  const int tileN = (sid & 7) * 384;     // 8 N-tiles

  const int srow = tid >> 2;
  const int scol = ((tid & 3) ^ ((tid >> 3) & 3)) * 8;
  const unsigned short* gA_s = A + (size_t)(tileM + srow) * 1024 + scol;
  const unsigned short* gB_s = B + (size_t)(tileN + srow) * 1024 + scol;

  // fragment read bases: chunk = lgrp ^ ((l15>>1)&3)  (conflict-free 2-way)
  const int fch  = (lgrp ^ ((l15 >> 1) & 3)) * 8;
  const int arow = (wm * 128 + l15) * 32 + fch;
  const int brow = (wn * 96 + l15) * 32 + fch;

  f32x4 acc[48] = {};   // [mt 0..7][nt 0..5] -> acc[mt*6+nt]

#define STG(S) do { const int _q = (S) & 3;                                \
    const unsigned short* _ga = gA_s + (S) * 32;                           \
    const unsigned short* _gb = gB_s + (S) * 32;                           \
    gload_lds16(_ga,          &lds[_q * 8192 + tid * 8]);                  \
    gload_lds16(_ga + 131072, &lds[_q * 8192 + 4096 + tid * 8]);           \
    gload_lds16(_gb,          &lds[32768 + _q * 12288 + tid * 8]);         \
    gload_lds16(_gb + 131072, &lds[32768 + _q * 12288 + 4096 + tid * 8]);  \
    gload_lds16(_gb + 262144, &lds[32768 + _q * 12288 + 8192 + tid * 8]);  \
  } while (0)

#define M24(MB)                                                            \
    acc[(MB+0)*6+0] = MFMA_BF16(a0_, b0_, acc[(MB+0)*6+0], 0, 0, 0);       \
    acc[(MB+0)*6+1] = MFMA_BF16(a0_, b1_, acc[(MB+0)*6+1], 0, 0, 0);       \
    acc[(MB+0)*6+2] = MFMA_BF16(a0_, b2_, acc[(MB+0)*6+2], 0, 0, 0);       \
    acc[(MB+0)*6+3] = MFMA_BF16(a0_, b3_, acc[(MB+0)*6+3], 0, 0, 0);       \
    acc[(MB+0)*6+4] = MFMA_BF16(a0_, b4_, acc[(MB+0)*6+4], 0, 0, 0);       \
    acc[(MB+0)*6+5] = MFMA_BF16(a0_, b5_, acc[(MB+0)*6+5], 0, 0, 0);       \
    acc[(MB+1)*6+0] = MFMA_BF16(a1_, b0_, acc[(MB+1)*6+0], 0, 0, 0);       \
    acc[(MB+1)*6+1] = MFMA_BF16(a1_, b1_, acc[(MB+1)*6+1], 0, 0, 0);       \
    acc[(MB+1)*6+2] = MFMA_BF16(a1_, b2_, acc[(MB+1)*6+2], 0, 0, 0);       \
    acc[(MB+1)*6+3] = MFMA_BF16(a1_, b3_, acc[(MB+1)*6+3], 0, 0, 0);       \
    acc[(MB+1)*6+4] = MFMA_BF16(a1_, b4_, acc[(MB+1)*6+4], 0, 0, 0);       \
    acc[(MB+1)*6+5] = MFMA_BF16(a1_, b5_, acc[(MB+1)*6+5], 0, 0, 0);       \
    acc[(MB+2)*6+0] = MFMA_BF16(a2_, b0_, acc[(MB+2)*6+0], 0, 0, 0);       \
    acc[(MB+2)*6+1] = MFMA_BF16(a2_, b1_, acc[(MB+2)*6+1], 0, 0, 0);       \
    acc[(MB+2)*6+2] = MFMA_BF16(a2_, b2_, acc[(MB+2)*6+2], 0, 0, 0);       \
    acc[(MB+2)*6+3] = MFMA_BF16(a2_, b3_, acc[(MB+2)*6+3], 0, 0, 0);       \
    acc[(MB+2)*6+4] = MFMA_BF16(a2_, b4_, acc[(MB+2)*6+4], 0, 0, 0);       \
    acc[(MB+2)*6+5] = MFMA_BF16(a2_, b5_, acc[(MB+2)*6+5], 0, 0, 0);       \
    acc[(MB+3)*6+0] = MFMA_BF16(a3_, b0_, acc[(MB+3)*6+0], 0, 0, 0);       \
    acc[(MB+3)*6+1] = MFMA_BF16(a3_, b1_, acc[(MB+3)*6+1], 0, 0, 0);       \
    acc[(MB+3)*6+2] = MFMA_BF16(a3_, b2_, acc[(MB+3)*6+2], 0, 0, 0);       \
    acc[(MB+3)*6+3] = MFMA_BF16(a3_, b3_, acc[(MB+3)*6+3], 0, 0, 0);       \
    acc[(MB+3)*6+4] = MFMA_BF16(a3_, b4_, acc[(MB+3)*6+4], 0, 0, 0);       \
    acc[(MB+3)*6+5] = MFMA_BF16(a3_, b5_, acc[(MB+3)*6+5], 0, 0, 0);

  // prologue: slabs 0,1,2 -> 15 outstanding
  STG(0); STG(1); STG(2);

#pragma unroll 1
  for (int p = 0; p < 32; ++p) {
    if (p < 30)       { asm volatile("s_waitcnt vmcnt(10)" ::: "memory"); }
    else if (p == 30) { asm volatile("s_waitcnt vmcnt(5)"  ::: "memory"); }
    else              { asm volatile("s_waitcnt vmcnt(0)"  ::: "memory"); }
    __builtin_amdgcn_sched_barrier(0);
    __builtin_amdgcn_s_barrier();

    if (p <= 28) STG(p + 3);

    const int slot = p & 3;
    const unsigned short* pa = &lds[slot * 8192 + arow];
    const unsigned short* pb = &lds[32768 + slot * 12288 + brow];

    bf16x8 b0_ = *(const bf16x8*)(pb);
    bf16x8 b1_ = *(const bf16x8*)(pb + 512);
    bf16x8 b2_ = *(const bf16x8*)(pb + 1024);
    bf16x8 b3_ = *(const bf16x8*)(pb + 1536);
    bf16x8 b4_ = *(const bf16x8*)(pb + 2048);
    bf16x8 b5_ = *(const bf16x8*)(pb + 2560);
    bf16x8 a0_ = *(const bf16x8*)(pa);
    bf16x8 a1_ = *(const bf16x8*)(pa + 512);
    bf16x8 a2_ = *(const bf16x8*)(pa + 1024);
    bf16x8 a3_ = *(const bf16x8*)(pa + 1536);
    asm volatile("s_waitcnt lgkmcnt(0)" ::: "memory");
    __builtin_amdgcn_sched_barrier(0);
    __builtin_amdgcn_s_setprio(1);
    M24(0)
    __builtin_amdgcn_s_setprio(0);

    a0_ = *(const bf16x8*)(pa + 2048);
    a1_ = *(const bf16x8*)(pa + 2560);
    a2_ = *(const bf16x8*)(pa + 3072);
    a3_ = *(const bf16x8*)(pa + 3584);
    asm volatile("s_waitcnt lgkmcnt(0)" ::: "memory");
    __builtin_amdgcn_sched_barrier(0);
    __builtin_amdgcn_s_setprio(1);
    M24(4)
    __builtin_amdgcn_s_setprio(0);
  }
#undef STG
#undef M24

  // epilogue: C/D layout col = lane&15 (B-row), row = lgrp*4 + rr (A-row)
#pragma unroll
  for (int nt = 0; nt < 6; ++nt) {
    const int col = tileN + wn * 96 + nt * 16 + l15;
    const float bs = bias[col];
#pragma unroll
    for (int mt = 0; mt < 8; ++mt) {
      const int row0 = tileM + wm * 128 + mt * 16 + lgrp * 4;
#pragma unroll
      for (int rr = 0; rr < 4; ++rr)
        C[(size_t)(row0 + rr) * 3072 + col] = f2bf(acc[mt * 6 + nt][rr] + bs);
    }
  }
}

// ---------------------------------------------------------------------------
// Out-proj GEMM (R13/R16-verified): C[8192,1024]f32 = A*B^T + bias.
// Tile 128x256, grid 64x4=256 (1 CU round), 8 waves 2Mx4N, per-wave 64x64.
// Slot = FULL K-tile (BK=64, 2 kh-slabs): A 16KB + B 32KB = 48KB; 3 slots
// = 144KB LDS. 6 gloads/thread/slot, distance-2 prefetch, gate vmcnt(6),
// 32 MFMA/gate as two sub-clusters (8 reads + lgkm(0) + 16 MFMA).
// ---------------------------------------------------------------------------
__global__ __launch_bounds__(512, 2) void gemm_outproj_kernel(
    const unsigned short* __restrict__ A,
    const unsigned short* __restrict__ B,
    const float* __restrict__ bias,
    float* __restrict__ Cv) {
  __shared__ __align__(16) unsigned short lds[73728];   // 144 KiB

  const int tid  = threadIdx.x;
  const int lane = tid & 63;
  const int wid  = tid >> 6;
  const int wm   = wid >> 2;       // 0..1  (M: 2 x 64)
  const int wn   = wid & 3;        // 0..3  (N: 4 x 64)
  const int lgrp = lane >> 4;
  const int l15  = lane & 15;

  const int sid = (blockIdx.x & 7) * 32 + (blockIdx.x >> 3);   // nwg = 256
  const int tileM = (sid >> 2) * 128;   // 64 M-tiles
  const int tileN = (sid & 3) * 256;    // 4 N-tiles

  const int srow = tid >> 2;
  const int scol = ((tid & 3) ^ ((tid >> 3) & 3)) * 8;
  const unsigned short* gA_s = A + (size_t)(tileM + srow) * 1024 + scol;
  const unsigned short* gB_s = B + (size_t)(tileN + srow) * 1024 + scol;

  const int fch  = (lgrp ^ ((l15 >> 1) & 3)) * 8;
  const int arow = (wm * 64 + l15) * 32 + fch;   // within 128x32 A slab
  const int brow = (wn * 64 + l15) * 32 + fch;   // within 256x32 B slab

  f32x4 acc[4][4] = {};

  // slot q base = q*24576; layout: A kh0 @0, A kh1 @4096, B kh0 @8192,
  // B kh1 @16384 (sizes: A slab 4096 ush, B slab 8192 ush)
#define STG(T) do { const int _q = (T) % 3;                                \
    const unsigned short* _ga = gA_s + (T) * 64;                           \
    const unsigned short* _gb = gB_s + (T) * 64;                           \
    gload_lds16(_ga,               &lds[_q * 24576 + tid * 8]);            \
    gload_lds16(_ga + 32,          &lds[_q * 24576 + 4096 + tid * 8]);     \
    gload_lds16(_gb,               &lds[_q * 24576 + 8192 + tid * 8]);     \
    gload_lds16(_gb + 131072,      &lds[_q * 24576 + 12288 + tid * 8]);    \
    gload_lds16(_gb + 32,          &lds[_q * 24576 + 16384 + tid * 8]);    \
    gload_lds16(_gb + 131072 + 32, &lds[_q * 24576 + 20480 + tid * 8]);    \
  } while (0)

#define SUB16(KH) do {                                                     \
    const unsigned short* _pa = &lds[slotb + (KH) * 4096 + arow];          \
    const unsigned short* _pb = &lds[slotb + 8192 + (KH) * 8192 + brow];   \
    bf16x8 a0_ = *(const bf16x8*)(_pa);                                    \
    bf16x8 a1_ = *(const bf16x8*)(_pa + 512);                              \
    bf16x8 a2_ = *(const bf16x8*)(_pa + 1024);                             \
    bf16x8 a3_ = *(const bf16x8*)(_pa + 1536);                             \
    bf16x8 nb0 = *(const bf16x8*)(_pb);                                    \
    bf16x8 nb1 = *(const bf16x8*)(_pb + 512);                              \
    bf16x8 nb2 = *(const bf16x8*)(_pb + 1024);                             \
    bf16x8 nb3 = *(const bf16x8*)(_pb + 1536);                             \
    asm volatile("s_waitcnt lgkmcnt(0)" ::: "memory");                     \
    __builtin_amdgcn_sched_barrier(0);                                     \
    __builtin_amdgcn_s_setprio(1);                                         \
    acc[0][0] = MFMA_BF16(a0_, nb0, acc[0][0], 0, 0, 0);                   \
    acc[0][1] = MFMA_BF16(a0_, nb1, acc[0][1], 0, 0, 0);                   \
    acc[0][2] = MFMA_BF16(a0_, nb2, acc[0][2], 0, 0, 0);                   \
    acc[0][3] = MFMA_BF16(a0_, nb3, acc[0][3], 0, 0, 0);                   \
    acc[1][0] = MFMA_BF16(a1_, nb0, acc[1][0], 0, 0, 0);                   \
    acc[1][1] = MFMA_BF16(a1_, nb1, acc[1][1], 0, 0, 0);                   \
    acc[1][2] = MFMA_BF16(a1_, nb2, acc[1][2], 0, 0, 0);                   \
    acc[1][3] = MFMA_BF16(a1_, nb3, acc[1][3], 0, 0, 0);                   \
    acc[2][0] = MFMA_BF16(a2_, nb0, acc[2][0], 0, 0, 0);                   \
    acc[2][1] = MFMA_BF16(a2_, nb1, acc[2][1], 0, 0, 0);                   \
    acc[2][2] = MFMA_BF16(a2_, nb2, acc[2][2], 0, 0, 0);                   \
    acc[2][3] = MFMA_BF16(a2_, nb3, acc[2][3], 0, 0, 0);                   \
    acc[3][0] = MFMA_BF16(a3_, nb0, acc[3][0], 0, 0, 0);                   \
    acc[3][1] = MFMA_BF16(a3_, nb1, acc[3][1], 0, 0, 0);                   \
    acc[3][2] = MFMA_BF16(a3_, nb2, acc[3][2], 0, 0, 0);                   \
    acc[3][3] = MFMA_BF16(a3_, nb3, acc[3][3], 0, 0, 0);                   \
    __builtin_amdgcn_s_setprio(0);                                         \
  } while (0)

  // prologue: K-tiles 0,1 -> 12 outstanding
  STG(0); STG(1);

#pragma unroll 1
  for (int p = 0; p < 16; ++p) {
    if (p < 15) { asm volatile("s_waitcnt vmcnt(6)" ::: "memory"); }
    else        { asm volatile("s_waitcnt vmcnt(0)" ::: "memory"); }
    __builtin_amdgcn_sched_barrier(0);
    __builtin_amdgcn_s_barrier();

    if (p <= 13) STG(p + 2);

    const int slotb = (p % 3) * 24576;
    SUB16(0);
    SUB16(1);
  }
#undef STG
#undef SUB16

#pragma unroll
  for (int nt = 0; nt < 4; ++nt) {
    const int col = tileN + wn * 64 + nt * 16 + l15;
    const float bs = bias[col];
#pragma unroll
    for (int mt = 0; mt < 4; ++mt) {
      const int row0 = tileM + wm * 64 + mt * 16 + lgrp * 4;
#pragma unroll
      for (int rr = 0; rr < 4; ++rr)
        Cv[(size_t)(row0 + rr) * 1024 + col] = acc[mt][nt][rr] + bs;
    }
  }
}

// ---------------------------------------------------------------------------
// Windowed attention v3 (MFMA). Block = (b, h, 64-query tile), 4 waves.
// ---------------------------------------------------------------------------
#define KST 72    // sK/sQ stride (bf16): 144B rows -> 2-way bank alias (free)
#define PST 104   // sVT/sP stride (bf16): 208B rows -> uniform 2-way

__global__ __launch_bounds__(256) void attn_local_kernel(
    const unsigned short* __restrict__ qkv, unsigned short* __restrict__ ctx) {
  __shared__ __align__(16) unsigned short sKP[96 * KST];   // K, later P
  __shared__ __align__(16) unsigned short sQ[64 * KST];
  __shared__ __align__(16) unsigned short sVT[64 * PST];

  const int tid  = threadIdx.x;
  const int lane = tid & 63;
  const int wid  = tid >> 6;
  const int qc   = lane & 15;        // query col within wave's 16
  const int lgrp = lane >> 4;        // 0..3

  const int qb = blockIdx.x & 15;    // S/64 = 16
  const int h  = (blockIdx.x >> 4) & 15;
  const int b  = blockIdx.x >> 8;
  const int i0 = qb * 64;

  const unsigned short* hb = qkv + (size_t)b * S_LEN * 3072 + (size_t)h * HD;

  // ---- stage K [96][KST] and V^T [64][PST] ----
#pragma unroll
  for (int it = 0; it < 3; ++it) {
    int c  = it * 256 + tid;         // 0..767
    int r  = c >> 3;                 // key row 0..95
    int d0 = (c & 7) * 8;            // dim chunk
    int j  = i0 - 16 + r;
    bf16x8 kv = {}, vv = {};
    if (0 <= j && j < S_LEN) {
      const unsigned short* rp = hb + (size_t)j * 3072;
      kv = *reinterpret_cast<const bf16x8*>(rp + DMODEL + d0);
      vv = *reinterpret_cast<const bf16x8*>(rp + 2 * DMODEL + d0);
    }
    *reinterpret_cast<bf16x8*>(&sKP[r * KST + d0]) = kv;
#pragma unroll
    for (int jj = 0; jj < 8; ++jj) {
      int dd = (jj + c) & 7;
      sVT[(d0 + dd) * PST + r] = (unsigned short)vv[dd];
    }
  }
  // ---- stage Q [64][KST] ----
#pragma unroll
  for (int it = 0; it < 2; ++it) {
    int c  = it * 256 + tid;         // 0..511
    int r  = c >> 3;                 // query row 0..63
    int d0 = (c & 7) * 8;
    bf16x8 qv = *reinterpret_cast<const bf16x8*>(hb + (size_t)(i0 + r) * 3072 + d0);
    *reinterpret_cast<bf16x8*>(&sQ[r * KST + d0]) = qv;
  }
  __syncthreads();

  const int q0 = wid * 16;

  // ---- phase 1: S^T = K @ Q^T  (12 MFMA) ----
  bf16x8 bq[2];
#pragma unroll
  for (int ks = 0; ks < 2; ++ks)
    bq[ks] = *reinterpret_cast<const bf16x8*>(
        &sQ[(q0 + qc) * KST + ks * 32 + lgrp * 8]);

  f32x4 st[6] = {};
#pragma unroll
  for (int kt = 0; kt < 6; ++kt) {
#pragma unroll
    for (int ks = 0; ks < 2; ++ks) {
      bf16x8 fa = *reinterpret_cast<const bf16x8*>(
          &sKP[(kt * 16 + qc) * KST + ks * 32 + lgrp * 8]);
      st[kt] = __builtin_amdgcn_mfma_f32_16x16x32_bf16(fa, bq[ks], st[kt], 0, 0, 0);
    }
  }
  __syncthreads();   // all waves done reading sKP before P overlays it

  // ---- mask + softmax ----
  const int q = q0 + qc;
  float pv[6][4];
  float mx = -3.0e38f;
#pragma unroll
  for (int kt = 0; kt < 6; ++kt)
#pragma unroll
    for (int rr = 0; rr < 4; ++rr) {
      int kk = kt * 16 + lgrp * 4 + rr;     // local key 0..95
      int j  = i0 - 16 + kk;
      bool ok = (j >= 0) && (j < S_LEN) && (kk >= q) && (kk <= q + 32);
      float s = ok ? st[kt][rr] * 0.125f : -3.0e38f;
      pv[kt][rr] = s;
      mx = fmaxf(mx, s);
    }
  mx = fmaxf(mx, __shfl_xor(mx, 16, 64));
  mx = fmaxf(mx, __shfl_xor(mx, 32, 64));

  float rsum = 0.f;
#pragma unroll
  for (int kt = 0; kt < 6; ++kt)
#pragma unroll
    for (int rr = 0; rr < 4; ++rr) {
      float p = __expf(pv[kt][rr] - mx);
      pv[kt][rr] = p;
      rsum += p;
    }
  rsum += __shfl_xor(rsum, 16, 64);
  rsum += __shfl_xor(rsum, 32, 64);
  const float inv = 1.0f / rsum;

  // ---- write unnormalized P bf16 into sP = sKP, layout [q][k] stride PST ----
  unsigned short* sP = sKP;
#pragma unroll
  for (int kt = 0; kt < 6; ++kt) {
    ushort4 w = make_ushort4(f2bf(pv[kt][0]), f2bf(pv[kt][1]),
                             f2bf(pv[kt][2]), f2bf(pv[kt][3]));
    *reinterpret_cast<ushort4*>(&sP[(q0 + qc) * PST + kt * 16 + lgrp * 4]) = w;
  }

  // ---- phase 2: ctx^T = V^T @ P^T  (12 MFMA) ----
  bf16x8 pb[3];
#pragma unroll
  for (int ks = 0; ks < 3; ++ks)
    pb[ks] = *reinterpret_cast<const bf16x8*>(
        &sP[(q0 + qc) * PST + ks * 32 + lgrp * 8]);

  f32x4 ct[4] = {};
#pragma unroll
  for (int dt = 0; dt < 4; ++dt)
#pragma unroll
    for (int ks = 0; ks < 3; ++ks) {
      bf16x8 fa = *reinterpret_cast<const bf16x8*>(
          &sVT[(dt * 16 + qc) * PST + ks * 32 + lgrp * 8]);
      ct[dt] = __builtin_amdgcn_mfma_f32_16x16x32_bf16(fa, pb[ks], ct[dt], 0, 0, 0);
    }

  // ---- epilogue ----
  unsigned short* op =
      ctx + ((size_t)b * S_LEN + i0 + q0 + qc) * DMODEL + h * HD;
#pragma unroll
  for (int dt = 0; dt < 4; ++dt) {
    ushort4 w = make_ushort4(
        f2bf(ct[dt][0] * inv), f2bf(ct[dt][1] * inv),
        f2bf(ct[dt][2] * inv), f2bf(ct[dt][3] * inv));
    *reinterpret_cast<ushort4*>(op + dt * 16 + lgrp * 4) = w;
  }
}

// ---------------------------------------------------------------------------
extern "C" void kernel_launch(void* const* d_in, const int* in_sizes, int n_in,
                              void* d_out, int out_size, void* d_ws, size_t ws_size,
                              hipStream_t stream) {
  const float* x     = (const float*)d_in[0];
  const float* w_in  = (const float*)d_in[1];
  const float* b_in  = (const float*)d_in[2];
  const float* w_out = (const float*)d_in[3];
  const float* b_out = (const float*)d_in[4];
  float* out = (float*)d_out;

  // workspace layout (bf16 = ushort), total ~92 MB
  unsigned short* xb   = (unsigned short*)d_ws;
  unsigned short* wib  = xb  + (size_t)8192 * 1024;
  unsigned short* wob  = wib + (size_t)3072 * 1024;
  unsigned short* qkv  = wob + (size_t)1024 * 1024;
  unsigned short* ctxb = qkv + (size_t)8192 * 3072;

  // fused f32->bf16 conversion (one launch)
  cvt_all_kernel<<<2048, 256, 0, stream>>>(x, w_in, w_out, xb, wib, wob);

  // QKV = x @ w_in^T + b_in -> [8192, 3072] bf16; tile 256x384, grid 256 (1 round)
  gemm_inproj_kernel<<<256, 512, 0, stream>>>(xb, wib, b_in, qkv);

  // windowed attention -> ctx [8192, 1024] bf16
  attn_local_kernel<<<BATCHN * NH * (S_LEN / 64), 256, 0, stream>>>(qkv, ctxb);

  // out = ctx @ w_out^T + b_out -> [8192, 1024] f32; tile 128x256, grid 256
  gemm_outproj_kernel<<<256, 512, 0, stream>>>(ctxb, wob, b_out, out);
}